// Round 1
// baseline (803.537 us; speedup 1.0000x reference)
//
#include <hip/hip_runtime.h>
#include <stdint.h>
#include <stddef.h>
#include <math.h>

// WindowAttention on MI355X (gfx950), bf16 MFMA pipeline.
// B=16 C=512 H=W=64 WS=16 HEADS=8 d=64 -> L=256 windows, N=256 positions.
// Attention batches = (n,h) = 2048, each 256x256 over d=64.
//
// Workspace layout (needs ~194 MB):
//   q   : bf16 [n][h][l][d]   67,108,864 B   (overwritten in-place by attn output o)
//   k   : bf16 [n][h][l][d]   67,108,864 B
//   v   : bf16 [n][h][l][d]   67,108,864 B
//   w1b : bf16 [1536][512]     1,572,864 B
//   w2b : bf16 [512][512]        524,288 B

typedef __bf16 bf16;
typedef __attribute__((ext_vector_type(8))) __bf16 bf16x8;
typedef __attribute__((ext_vector_type(4))) __bf16 bf16x4;
typedef __attribute__((ext_vector_type(4))) float f32x4;

#define MFMA16(A, B, C) __builtin_amdgcn_mfma_f32_16x16x32_bf16((A), (B), (C), 0, 0, 0)

__device__ __forceinline__ float fast_exp2(float x) {
#if __has_builtin(__builtin_amdgcn_exp2f)
  return __builtin_amdgcn_exp2f(x);
#else
  return exp2f(x);
#endif
}

// ---------------------------------------------------------------- cvt weights
__global__ void cvt_fp32_bf16(const float* __restrict__ src, bf16* __restrict__ dst) {
  int i = (blockIdx.x * blockDim.x + threadIdx.x) * 4;  // grid sized exactly
  float4 f = *(const float4*)(src + i);
  bf16x4 r;
  r[0] = (bf16)f.x; r[1] = (bf16)f.y; r[2] = (bf16)f.z; r[3] = (bf16)f.w;
  *(bf16x4*)(dst + i) = r;
}

#define LDA 520  // 512 + 8 bf16 pad: row stride 1040 B (16B-aligned, 4-dword bank shift)

// ---------------------------------------------------------------- QKV GEMM
// A-resident: block = 128 M-rows (one window l, half of n-range) x full K=512 in LDS.
// Loops 12 N-chunks of 128; B-frags loaded global->VGPR (L2-hot, 1.5MB weights).
// No barriers inside the K loop.
__global__ void __launch_bounds__(512, 2) gemm_qkv(
    const float* __restrict__ x, const bf16* __restrict__ w1,
    const float* __restrict__ b1,
    bf16* __restrict__ qo, bf16* __restrict__ ko, bf16* __restrict__ vo) {
  extern __shared__ bf16 Al[];  // [128][LDA]
  const int tid = threadIdx.x;
  const int bm  = blockIdx.x;           // 0..511
  const int l   = bm >> 1;              // window index
  const int n0  = (bm & 1) << 7;        // n-half
  const int b   = l >> 4, ih = (l >> 2) & 3, iw = l & 3;
  const int h0  = ih * 16 + (n0 >> 4);
  const int w0  = iw * 16;

  // stage A strip: 128 n-rows x 512 c, fp32 gather -> bf16 LDS
  for (int j = 0; j < 32; ++j) {
    int f4  = j * 512 + tid;            // 0..16383 float4s
    int c   = f4 >> 5;                  // 0..511
    int qq  = f4 & 31;
    int wsh = qq >> 2;                  // 0..7
    int w4  = (qq & 3) << 2;            // 0,4,8,12
    float4 xf = *(const float4*)(x + (((b * 512 + c) * 64 + h0 + wsh) * 64 + w0 + w4));
    int nl = wsh * 16 + w4;             // local row (n - n0)
    bf16* d = &Al[nl * LDA + c];
    d[0]       = (bf16)xf.x;
    d[LDA]     = (bf16)xf.y;
    d[2 * LDA] = (bf16)xf.z;
    d[3 * LDA] = (bf16)xf.w;
  }
  __syncthreads();

  const int wave = tid >> 6, lane = tid & 63;
  const int l15 = lane & 15, quad = lane >> 4;
  const int wr = wave >> 2, wc = wave & 3;  // 2x4 wave grid, each wave 64x32
  const int R = wr * 64;
  const f32x4 fz = {0.f, 0.f, 0.f, 0.f};

  for (int nc = 0; nc < 12; ++nc) {
    const int t0 = nc * 128 + wc * 32;
    f32x4 acc[4][2];
#pragma unroll
    for (int a = 0; a < 4; ++a) { acc[a][0] = fz; acc[a][1] = fz; }
    for (int ks = 0; ks < 16; ++ks) {
      bf16x8 af[4];
#pragma unroll
      for (int lt = 0; lt < 4; ++lt)
        af[lt] = *(const bf16x8*)&Al[(R + lt * 16 + l15) * LDA + ks * 32 + quad * 8];
      bf16x8 bfr[2];
#pragma unroll
      for (int ct = 0; ct < 2; ++ct)
        bfr[ct] = *(const bf16x8*)&w1[(size_t)(t0 + ct * 16 + l15) * 512 + ks * 32 + quad * 8];
#pragma unroll
      for (int lt = 0; lt < 4; ++lt)
#pragma unroll
        for (int ct = 0; ct < 2; ++ct)
          acc[lt][ct] = MFMA16(af[lt], bfr[ct], acc[lt][ct]);
    }
    // epilogue: scatter to q/k/v [n][h][l][d] bf16, q scaled by d^-0.5 after bias
#pragma unroll
    for (int ct = 0; ct < 2; ++ct) {
      const int t = t0 + ct * 16 + l15;   // output col, wave-uniform which/h
      const int which = t >> 9;
      const int cc = t & 511;
      const int hh = cc >> 6, dd = cc & 63;
      const float bias = b1[t];
      bf16* dst = (which == 0) ? qo : (which == 1) ? ko : vo;
      const float scale = (which == 0) ? 0.125f : 1.0f;
#pragma unroll
      for (int lt = 0; lt < 4; ++lt) {
#pragma unroll
        for (int r = 0; r < 4; ++r) {
          int n = n0 + R + lt * 16 + quad * 4 + r;
          float val = (acc[lt][ct][r] + bias) * scale;
          dst[((n * 8 + hh) * 256 + l) * 64 + dd] = (bf16)val;
        }
      }
    }
  }
}

// ---------------------------------------------------------------- attention
// One block per (n,h). K in LDS [256][72], V^T in LDS [64][264],
// per-wave P buffer [16][264]. Output written in-place over q.
__global__ void __launch_bounds__(512, 2) attn_win(
    bf16* __restrict__ qio, const bf16* __restrict__ kg, const bf16* __restrict__ vg) {
  extern __shared__ bf16 sm[];
  bf16* Kl = sm;                 // 256*72  = 18432 elems
  bf16* Vt = sm + 256 * 72;      // 64*264  = 16896 elems
  bf16* Pl = Vt + 64 * 264;      // 8*16*264 = 33792 elems
  const int tid = threadIdx.x;
  const int bb = blockIdx.x;     // 0..2047
  const int n = bb >> 3, h = bb & 7;
  const size_t base = (size_t)(n * 8 + h) * 16384;
  const bf16* Kg = kg + base;
  const bf16* Vg = vg + base;
  bf16* Qg = qio + base;

  for (int j = 0; j < 4; ++j) {  // K: [m][d] -> [m][72]
    int cc = j * 512 + tid;
    int m = cc >> 3, dc = cc & 7;
    bf16x8 t = *(const bf16x8*)(Kg + m * 64 + dc * 8);
    *(bf16x8*)&Kl[m * 72 + dc * 8] = t;
  }
  for (int j = 0; j < 4; ++j) {  // V: [m][d] -> V^T [d][264]
    int cc = j * 512 + tid;
    int dc = cc >> 8, m = cc & 255;
    bf16x8 t = *(const bf16x8*)(Vg + m * 64 + dc * 8);
#pragma unroll
    for (int s = 0; s < 8; ++s) Vt[(dc * 8 + s) * 264 + m] = t[s];
  }

  const int wave = tid >> 6, lane = tid & 63;
  const int l15 = lane & 15, quad = lane >> 4;
  const int lb = wave * 32;           // 32 query rows per wave
  bf16* Pw = Pl + wave * 16 * 264;

  // Q frags (global, A-layout) loaded before any in-place overwrite
  bf16x8 qf[2][2];
#pragma unroll
  for (int lt = 0; lt < 2; ++lt)
#pragma unroll
    for (int ks = 0; ks < 2; ++ks)
      qf[lt][ks] = *(const bf16x8*)(Qg + (lb + lt * 16 + l15) * 64 + ks * 32 + quad * 8);

  __syncthreads();

  const f32x4 fz = {0.f, 0.f, 0.f, 0.f};
  const float LOG2E = 1.44269504088896340736f;
  for (int lt = 0; lt < 2; ++lt) {
    f32x4 s[16];
#pragma unroll
    for (int mt = 0; mt < 16; ++mt) s[mt] = fz;
#pragma unroll
    for (int mt = 0; mt < 16; ++mt)
#pragma unroll
      for (int ks = 0; ks < 2; ++ks) {
        bf16x8 kf = *(const bf16x8*)&Kl[(mt * 16 + l15) * 72 + ks * 32 + quad * 8];
        s[mt] = MFMA16(qf[lt][ks], kf, s[mt]);
      }
    // softmax over m: C-layout row = quad*4+reg, col(m) = lane&15 across 16 frags
    float rmax[4], rsum[4];
#pragma unroll
    for (int r = 0; r < 4; ++r) {
      float mx = s[0][r];
#pragma unroll
      for (int mt = 1; mt < 16; ++mt) mx = fmaxf(mx, s[mt][r]);
#pragma unroll
      for (int xo = 1; xo < 16; xo <<= 1) mx = fmaxf(mx, __shfl_xor(mx, xo, 16));
      rmax[r] = mx;
      rsum[r] = 0.f;
    }
#pragma unroll
    for (int mt = 0; mt < 16; ++mt) {
#pragma unroll
      for (int r = 0; r < 4; ++r) {
        float p = fast_exp2((s[mt][r] - rmax[r]) * LOG2E);
        bf16 pb = (bf16)p;
        rsum[r] += (float)pb;
        Pw[(quad * 4 + r) * 264 + mt * 16 + l15] = pb;  // C-layout -> A-layout via LDS
      }
    }
#pragma unroll
    for (int r = 0; r < 4; ++r)
#pragma unroll
      for (int xo = 1; xo < 16; xo <<= 1) rsum[r] += __shfl_xor(rsum[r], xo, 16);

    // PV: O[l][d] = sum_m P[l][m] V[m][d]
    bf16x8 pf[8];
#pragma unroll
    for (int mk = 0; mk < 8; ++mk)
      pf[mk] = *(const bf16x8*)&Pw[l15 * 264 + mk * 32 + quad * 8];
    f32x4 of[4];
#pragma unroll
    for (int dt = 0; dt < 4; ++dt) of[dt] = fz;
#pragma unroll
    for (int dt = 0; dt < 4; ++dt)
#pragma unroll
      for (int mk = 0; mk < 8; ++mk) {
        bf16x8 vf = *(const bf16x8*)&Vt[(dt * 16 + l15) * 264 + mk * 32 + quad * 8];
        of[dt] = MFMA16(pf[mk], vf, of[dt]);
      }
    float inv[4];
#pragma unroll
    for (int r = 0; r < 4; ++r) inv[r] = 1.0f / rsum[r];
#pragma unroll
    for (int dt = 0; dt < 4; ++dt)
#pragma unroll
      for (int r = 0; r < 4; ++r)
        Qg[(lb + lt * 16 + quad * 4 + r) * 64 + dt * 16 + l15] = (bf16)(of[dt][r] * inv[r]);
  }
}

// ---------------------------------------------------------------- out proj
__global__ void __launch_bounds__(512, 2) gemm_out(
    const bf16* __restrict__ og, const bf16* __restrict__ w2,
    const float* __restrict__ b2, float* __restrict__ out) {
  extern __shared__ bf16 Al[];  // [128][LDA]
  const int tid = threadIdx.x;
  const int bm = blockIdx.x;    // 0..511
  const int l = bm >> 1;
  const int n0 = (bm & 1) << 7;
  const int b = l >> 4, ih = (l >> 2) & 3, iw = l & 3;

  for (int j = 0; j < 16; ++j) {  // A: o[n][h][l][d] gather -> LDS [128 n][512 c]
    int cc = j * 512 + tid;       // 0..8191 chunks of 8
    int nl = cc >> 6;
    int ch = cc & 63;
    int hh = ch >> 3, d8 = (ch & 7) * 8;
    bf16x8 t = *(const bf16x8*)(og + ((size_t)((n0 + nl) * 8 + hh) * 256 + l) * 64 + d8);
    *(bf16x8*)&Al[nl * LDA + ch * 8] = t;
  }
  __syncthreads();

  const int wave = tid >> 6, lane = tid & 63;
  const int l15 = lane & 15, quad = lane >> 4;
  const int wr = wave >> 2, wc = wave & 3;
  const int R = wr * 64;
  const f32x4 fz = {0.f, 0.f, 0.f, 0.f};

  for (int nc = 0; nc < 4; ++nc) {
    const int t0 = nc * 128 + wc * 32;
    f32x4 acc[4][2];
#pragma unroll
    for (int a = 0; a < 4; ++a) { acc[a][0] = fz; acc[a][1] = fz; }
    for (int ks = 0; ks < 16; ++ks) {
      bf16x8 af[4];
#pragma unroll
      for (int lt = 0; lt < 4; ++lt)
        af[lt] = *(const bf16x8*)&Al[(R + lt * 16 + l15) * LDA + ks * 32 + quad * 8];
      bf16x8 bfr[2];
#pragma unroll
      for (int ct = 0; ct < 2; ++ct)
        bfr[ct] = *(const bf16x8*)&w2[(size_t)(t0 + ct * 16 + l15) * 512 + ks * 32 + quad * 8];
#pragma unroll
      for (int lt = 0; lt < 4; ++lt)
#pragma unroll
        for (int ct = 0; ct < 2; ++ct)
          acc[lt][ct] = MFMA16(af[lt], bfr[ct], acc[lt][ct]);
    }
    // epilogue: + bias, write fp32 to (B,C,H,W); 4 regs = 4 consecutive w -> float4
#pragma unroll
    for (int ct = 0; ct < 2; ++ct) {
      const int t = t0 + ct * 16 + l15;  // c_out
      const float bias = b2[t];
#pragma unroll
      for (int lt = 0; lt < 4; ++lt) {
        int n = n0 + R + lt * 16 + quad * 4;
        int wsh = n >> 4, wsw = n & 15;
        float4 vv;
        vv.x = acc[lt][ct][0] + bias;
        vv.y = acc[lt][ct][1] + bias;
        vv.z = acc[lt][ct][2] + bias;
        vv.w = acc[lt][ct][3] + bias;
        *(float4*)(out + (((size_t)b * 512 + t) * 64 + ih * 16 + wsh) * 64 + iw * 16 + wsw) = vv;
      }
    }
  }
}

// ---------------------------------------------------------------- launch
extern "C" void kernel_launch(void* const* d_in, const int* in_sizes, int n_in,
                              void* d_out, int out_size, void* d_ws, size_t ws_size,
                              hipStream_t stream) {
  (void)in_sizes; (void)n_in; (void)out_size; (void)ws_size;
  const float* x   = (const float*)d_in[0];
  const float* w1f = (const float*)d_in[1];
  const float* b1  = (const float*)d_in[2];
  const float* w2f = (const float*)d_in[3];
  const float* b2  = (const float*)d_in[4];
  float* out = (float*)d_out;

  char* ws = (char*)d_ws;
  bf16* q   = (bf16*)(ws);
  bf16* k   = (bf16*)(ws + 67108864ull);
  bf16* v   = (bf16*)(ws + 134217728ull);
  bf16* w1b = (bf16*)(ws + 201326592ull);
  bf16* w2b = (bf16*)(ws + 201326592ull + 1572864ull);
  // total ws use: 203,423,744 B

  const int LDS_GEMM = 128 * LDA * 2;                       // 133,120 B
  const int LDS_ATTN = (256 * 72 + 64 * 264 + 8 * 16 * 264) * 2;  // 138,240 B
  hipFuncSetAttribute(reinterpret_cast<const void*>(gemm_qkv),
                      hipFuncAttributeMaxDynamicSharedMemorySize, LDS_GEMM);
  hipFuncSetAttribute(reinterpret_cast<const void*>(attn_win),
                      hipFuncAttributeMaxDynamicSharedMemorySize, LDS_ATTN);
  hipFuncSetAttribute(reinterpret_cast<const void*>(gemm_out),
                      hipFuncAttributeMaxDynamicSharedMemorySize, LDS_GEMM);

  hipLaunchKernelGGL(cvt_fp32_bf16, dim3(768), dim3(256), 0, stream, w1f, w1b);
  hipLaunchKernelGGL(cvt_fp32_bf16, dim3(256), dim3(256), 0, stream, w2f, w2b);
  hipLaunchKernelGGL(gemm_qkv, dim3(512), dim3(512), LDS_GEMM, stream, x, w1b, b1, q, k, v);
  hipLaunchKernelGGL(attn_win, dim3(2048), dim3(512), LDS_ATTN, stream, q, k, v);
  hipLaunchKernelGGL(gemm_out, dim3(512), dim3(512), LDS_GEMM, stream, q, w2b, b2, out);
}

// Round 2
// 690.103 us; speedup vs baseline: 1.1644x; 1.1644x over previous
//
#include <hip/hip_runtime.h>
#include <stdint.h>
#include <stddef.h>
#include <math.h>

// WindowAttention MI355X (gfx950). B=16 C=512 H=W=64 WS=16 HEADS=8 d=64.
// L=256 windows, N=256 positions, attention batches (n,h)=2048 of 256x256,d=64.
//
// Workspace: q[n][h][l][d] 67MB (o overwrites in-place) | k 67MB | v 67MB |
//            w1b bf16 1.5MB | w2b bf16 0.5MB.  Total ~203 MB.

typedef __bf16 bf16;
typedef __attribute__((ext_vector_type(8))) __bf16 bf16x8;
typedef __attribute__((ext_vector_type(4))) __bf16 bf16x4;
typedef __attribute__((ext_vector_type(4))) float f32x4;

#define MFMA16(A, B, C) __builtin_amdgcn_mfma_f32_16x16x32_bf16((A), (B), (C), 0, 0, 0)

__device__ __forceinline__ float fast_exp2(float x) { return exp2f(x); }

// XOR-swizzled A-tile element index: 128 rows x 512 cols bf16, unpadded 131072 B.
// granule (16B) index = (c>>3) ^ (n>>4 & 7) ^ (n & 7): spreads both the
// n-strided staging writes (was 16-way conflict) and the b128 frag reads.
__device__ __forceinline__ int aswz(int n, int c) {
  int g = (c >> 3) ^ ((n >> 4) & 7) ^ (n & 7);
  return n * 512 + (g << 3) + (c & 7);
}

// ---------------------------------------------------------------- cvt weights
__global__ void cvt_fp32_bf16(const float* __restrict__ src, bf16* __restrict__ dst) {
  int i = (blockIdx.x * blockDim.x + threadIdx.x) * 4;
  float4 f = *(const float4*)(src + i);
  bf16x4 r;
  r[0] = (bf16)f.x; r[1] = (bf16)f.y; r[2] = (bf16)f.z; r[3] = (bf16)f.w;
  *(bf16x4*)(dst + i) = r;
}

// ---------------------------------------------------------------- QKV GEMM
// A-resident: block = 128 rows (window l, n-half) x K=512 in swizzled LDS.
// Waves 2x4; per wave per chunk: 64 rows x 64 couts (16 MFMA : 4 ds_read_b128).
// 6 cout-chunks of 256. Epilogue: per-wave LDS transpose -> 128B dwordx4 stores.
__global__ void __launch_bounds__(512, 2) gemm_qkv(
    const float* __restrict__ x, const bf16* __restrict__ w1,
    const float* __restrict__ b1,
    bf16* __restrict__ qo, bf16* __restrict__ ko, bf16* __restrict__ vo) {
  extern __shared__ bf16 Al[];              // 128*512 swizzled + epilogue buf
  bf16* Ep = Al + 128 * 512;                // 8 waves x [16][72]
  const int tid = threadIdx.x;
  const int bm  = blockIdx.x;               // 0..511
  const int l   = bm >> 1;
  const int n0  = (bm & 1) << 7;
  const int b   = l >> 4, ih = (l >> 2) & 3, iw = l & 3;
  const int h0  = ih * 16 + (n0 >> 4);
  const int w0  = iw * 16;

  // stage A: 128 n-rows x 512 c, fp32 gather -> bf16 swizzled LDS
  for (int j = 0; j < 32; ++j) {
    int f4  = j * 512 + tid;
    int c   = f4 >> 5;
    int qq  = f4 & 31;
    int wsh = qq >> 2;
    int w4  = (qq & 3) << 2;
    float4 xf = *(const float4*)(x + (((b * 512 + c) * 64 + h0 + wsh) * 64 + w0 + w4));
    int nb = wsh * 16 + w4;
    Al[aswz(nb + 0, c)] = (bf16)xf.x;
    Al[aswz(nb + 1, c)] = (bf16)xf.y;
    Al[aswz(nb + 2, c)] = (bf16)xf.z;
    Al[aswz(nb + 3, c)] = (bf16)xf.w;
  }
  __syncthreads();

  const int wave = tid >> 6, lane = tid & 63;
  const int l15 = lane & 15, quad = lane >> 4;
  const int wr = wave >> 2, wc = wave & 3;   // 2x4 wave grid
  const int R = wr * 64;
  bf16* Epw = Ep + wave * 16 * 72;
  const f32x4 fz = {0.f, 0.f, 0.f, 0.f};

  for (int nc = 0; nc < 6; ++nc) {
    const int t0w = nc * 256 + wc * 64;      // 64-aligned -> which/hh wave-uniform
    f32x4 acc[4][4];
#pragma unroll
    for (int a = 0; a < 4; ++a)
#pragma unroll
      for (int c2 = 0; c2 < 4; ++c2) acc[a][c2] = fz;

    bf16x8 bfr[4];
#pragma unroll
    for (int ct = 0; ct < 4; ++ct)
      bfr[ct] = *(const bf16x8*)&w1[(size_t)(t0w + ct * 16 + l15) * 512 + quad * 8];
#pragma unroll
    for (int ks = 0; ks < 16; ++ks) {
      bf16x8 bnx[4];
      if (ks < 15) {
#pragma unroll
        for (int ct = 0; ct < 4; ++ct)
          bnx[ct] = *(const bf16x8*)&w1[(size_t)(t0w + ct * 16 + l15) * 512 + (ks + 1) * 32 + quad * 8];
      }
      bf16x8 af[4];
#pragma unroll
      for (int lt = 0; lt < 4; ++lt)
        af[lt] = *(const bf16x8*)&Al[aswz(R + lt * 16 + l15, ks * 32 + quad * 8)];
#pragma unroll
      for (int lt = 0; lt < 4; ++lt)
#pragma unroll
        for (int ct = 0; ct < 4; ++ct)
          acc[lt][ct] = MFMA16(af[lt], bfr[ct], acc[lt][ct]);
#pragma unroll
      for (int ct = 0; ct < 4; ++ct) bfr[ct] = bnx[ct];
    }

    // epilogue: wave-private transpose -> 128B contiguous bf16x8 stores
    const int which = t0w >> 9;
    const int hh = (t0w & 511) >> 6;
    bf16* dst = (which == 0) ? qo : (which == 1) ? ko : vo;
    const float scale = (which == 0) ? 0.125f : 1.0f;
    float bias[4];
#pragma unroll
    for (int ct = 0; ct < 4; ++ct) bias[ct] = b1[t0w + ct * 16 + l15];

#pragma unroll
    for (int lt = 0; lt < 4; ++lt) {
#pragma unroll
      for (int ct = 0; ct < 4; ++ct)
#pragma unroll
        for (int r = 0; r < 4; ++r)
          Epw[(quad * 4 + r) * 72 + ct * 16 + l15] =
              (bf16)((acc[lt][ct][r] + bias[ct]) * scale);
      const int rr = lane >> 3, ch8 = (lane & 7) * 8;
#pragma unroll
      for (int half = 0; half < 2; ++half) {
        int row = half * 8 + rr;
        bf16x8 vv = *(const bf16x8*)&Epw[row * 72 + ch8];
        int n = n0 + R + lt * 16 + row;
        *(bf16x8*)&dst[((size_t)(n * 8 + hh) * 256 + l) * 64 + ch8] = vv;
      }
    }
  }
}

// ---------------------------------------------------------------- attention
// One block per (n,h). K LDS [256][72], V^T LDS [64][264], per-wave P [16][264].
// Output overwrites q in-place; writes via per-wave transpose -> 128B chunks.
__global__ void __launch_bounds__(512, 2) attn_win(
    bf16* __restrict__ qio, const bf16* __restrict__ kg, const bf16* __restrict__ vg) {
  extern __shared__ bf16 sm[];
  bf16* Kl = sm;
  bf16* Vt = sm + 256 * 72;
  bf16* Pl = Vt + 64 * 264;
  const int tid = threadIdx.x;
  const int bb = blockIdx.x;
  const int n = bb >> 3, h = bb & 7;
  const size_t base = (size_t)(n * 8 + h) * 16384;
  const bf16* Kg = kg + base;
  const bf16* Vg = vg + base;
  bf16* Qg = qio + base;

  for (int j = 0; j < 4; ++j) {
    int cc = j * 512 + tid;
    int m = cc >> 3, dc = cc & 7;
    bf16x8 t = *(const bf16x8*)(Kg + m * 64 + dc * 8);
    *(bf16x8*)&Kl[m * 72 + dc * 8] = t;
  }
  for (int j = 0; j < 4; ++j) {
    int cc = j * 512 + tid;
    int dc = cc >> 8, m = cc & 255;
    bf16x8 t = *(const bf16x8*)(Vg + m * 64 + dc * 8);
#pragma unroll
    for (int s = 0; s < 8; ++s) Vt[(dc * 8 + s) * 264 + m] = t[s];
  }

  const int wave = tid >> 6, lane = tid & 63;
  const int l15 = lane & 15, quad = lane >> 4;
  const int lb = wave * 32;
  bf16* Pw = Pl + wave * 16 * 264;

  bf16x8 qf[2][2];
#pragma unroll
  for (int lt = 0; lt < 2; ++lt)
#pragma unroll
    for (int ks = 0; ks < 2; ++ks)
      qf[lt][ks] = *(const bf16x8*)(Qg + (lb + lt * 16 + l15) * 64 + ks * 32 + quad * 8);

  __syncthreads();

  const f32x4 fz = {0.f, 0.f, 0.f, 0.f};
  const float LOG2E = 1.44269504088896340736f;
  for (int lt = 0; lt < 2; ++lt) {
    f32x4 s[16];
#pragma unroll
    for (int mt = 0; mt < 16; ++mt) s[mt] = fz;
#pragma unroll
    for (int mt = 0; mt < 16; ++mt)
#pragma unroll
      for (int ks = 0; ks < 2; ++ks) {
        bf16x8 kf = *(const bf16x8*)&Kl[(mt * 16 + l15) * 72 + ks * 32 + quad * 8];
        s[mt] = MFMA16(qf[lt][ks], kf, s[mt]);
      }
    float rmax[4], rsum[4];
#pragma unroll
    for (int r = 0; r < 4; ++r) {
      float mx = s[0][r];
#pragma unroll
      for (int mt = 1; mt < 16; ++mt) mx = fmaxf(mx, s[mt][r]);
#pragma unroll
      for (int xo = 1; xo < 16; xo <<= 1) mx = fmaxf(mx, __shfl_xor(mx, xo, 16));
      rmax[r] = mx;
      rsum[r] = 0.f;
    }
#pragma unroll
    for (int mt = 0; mt < 16; ++mt) {
#pragma unroll
      for (int r = 0; r < 4; ++r) {
        float p = fast_exp2((s[mt][r] - rmax[r]) * LOG2E);
        bf16 pb = (bf16)p;
        rsum[r] += (float)pb;
        Pw[(quad * 4 + r) * 264 + mt * 16 + l15] = pb;
      }
    }
#pragma unroll
    for (int r = 0; r < 4; ++r)
#pragma unroll
      for (int xo = 1; xo < 16; xo <<= 1) rsum[r] += __shfl_xor(rsum[r], xo, 16);

    bf16x8 pf[8];
#pragma unroll
    for (int mk = 0; mk < 8; ++mk)
      pf[mk] = *(const bf16x8*)&Pw[l15 * 264 + mk * 32 + quad * 8];
    f32x4 of[4];
#pragma unroll
    for (int dt = 0; dt < 4; ++dt) of[dt] = fz;
#pragma unroll
    for (int dt = 0; dt < 4; ++dt)
#pragma unroll
      for (int mk = 0; mk < 8; ++mk) {
        bf16x8 vf = *(const bf16x8*)&Vt[(dt * 16 + l15) * 264 + mk * 32 + quad * 8];
        of[dt] = MFMA16(pf[mk], vf, of[dt]);
      }
    float inv[4];
#pragma unroll
    for (int r = 0; r < 4; ++r) inv[r] = 1.0f / rsum[r];

    // o-write: per-wave transpose (reuse Pw) -> 128B contiguous bf16x8 stores
    bf16* Ew = Pw;  // [16][72] region
#pragma unroll
    for (int dt = 0; dt < 4; ++dt)
#pragma unroll
      for (int r = 0; r < 4; ++r)
        Ew[(quad * 4 + r) * 72 + dt * 16 + l15] = (bf16)(of[dt][r] * inv[r]);
    const int rr = lane >> 3, ch8 = (lane & 7) * 8;
#pragma unroll
    for (int half = 0; half < 2; ++half) {
      int row = half * 8 + rr;
      bf16x8 vv = *(const bf16x8*)&Ew[row * 72 + ch8];
      *(bf16x8*)(Qg + (lb + lt * 16 + row) * 64 + ch8) = vv;
    }
  }
}

// ---------------------------------------------------------------- out proj
// Swapped MFMA operands: D = W2 x O^T, C-layout row=cout col=n, so stores are
// 64B-contiguous fp32 along w. No epilogue LDS needed.
__global__ void __launch_bounds__(512, 2) gemm_out(
    const bf16* __restrict__ og, const bf16* __restrict__ w2,
    const float* __restrict__ b2, float* __restrict__ out) {
  extern __shared__ bf16 Al[];  // 128*512 swizzled
  const int tid = threadIdx.x;
  const int bm = blockIdx.x;
  const int l = bm >> 1;
  const int n0 = (bm & 1) << 7;
  const int b = l >> 4, ih = (l >> 2) & 3, iw = l & 3;

  for (int j = 0; j < 16; ++j) {  // o[n][h][l][d] gather -> swizzled LDS rows
    int cc = j * 512 + tid;
    int nl = cc >> 6;
    int ch = cc & 63;
    int hh = ch >> 3, d8 = (ch & 7) * 8;
    bf16x8 t = *(const bf16x8*)(og + ((size_t)((n0 + nl) * 8 + hh) * 256 + l) * 64 + d8);
    *(bf16x8*)&Al[aswz(nl, ch * 8)] = t;
  }
  __syncthreads();

  const int wave = tid >> 6, lane = tid & 63;
  const int l15 = lane & 15, quad = lane >> 4;
  const int wr = wave >> 2, wc = wave & 3;
  const int R = wr * 64;
  const f32x4 fz = {0.f, 0.f, 0.f, 0.f};

  for (int nc = 0; nc < 2; ++nc) {
    const int t0w = nc * 256 + wc * 64;
    f32x4 acc[4][4];
#pragma unroll
    for (int a = 0; a < 4; ++a)
#pragma unroll
      for (int c2 = 0; c2 < 4; ++c2) acc[a][c2] = fz;

    bf16x8 bfr[4];
#pragma unroll
    for (int ct = 0; ct < 4; ++ct)
      bfr[ct] = *(const bf16x8*)&w2[(size_t)(t0w + ct * 16 + l15) * 512 + quad * 8];
#pragma unroll
    for (int ks = 0; ks < 16; ++ks) {
      bf16x8 bnx[4];
      if (ks < 15) {
#pragma unroll
        for (int ct = 0; ct < 4; ++ct)
          bnx[ct] = *(const bf16x8*)&w2[(size_t)(t0w + ct * 16 + l15) * 512 + (ks + 1) * 32 + quad * 8];
      }
      bf16x8 af[4];
#pragma unroll
      for (int lt = 0; lt < 4; ++lt)
        af[lt] = *(const bf16x8*)&Al[aswz(R + lt * 16 + l15, ks * 32 + quad * 8)];
#pragma unroll
      for (int lt = 0; lt < 4; ++lt)
#pragma unroll
        for (int ct = 0; ct < 4; ++ct)
          acc[lt][ct] = MFMA16(bfr[ct], af[lt], acc[lt][ct]);  // swapped: rows=cout
#pragma unroll
      for (int ct = 0; ct < 4; ++ct) bfr[ct] = bnx[ct];
    }

#pragma unroll
    for (int ct = 0; ct < 4; ++ct) {
      float4 bias4 = *(const float4*)&b2[t0w + ct * 16 + quad * 4];
#pragma unroll
      for (int lt = 0; lt < 4; ++lt) {
        const int nbase = n0 + R + lt * 16;   // mult of 16 -> wsh uniform
        const int wsh = nbase >> 4;
        size_t rowbase = (((size_t)b * 512) * 64 + (size_t)ih * 16 + wsh) * 64 + iw * 16 + l15;
#pragma unroll
        for (int r = 0; r < 4; ++r) {
          int cout = t0w + ct * 16 + quad * 4 + r;
          out[rowbase + (size_t)cout * 4096] = acc[lt][ct][r] + ((const float*)&bias4)[r];
        }
      }
    }
  }
}

// ---------------------------------------------------------------- launch
extern "C" void kernel_launch(void* const* d_in, const int* in_sizes, int n_in,
                              void* d_out, int out_size, void* d_ws, size_t ws_size,
                              hipStream_t stream) {
  (void)in_sizes; (void)n_in; (void)out_size; (void)ws_size;
  const float* x   = (const float*)d_in[0];
  const float* w1f = (const float*)d_in[1];
  const float* b1  = (const float*)d_in[2];
  const float* w2f = (const float*)d_in[3];
  const float* b2  = (const float*)d_in[4];
  float* out = (float*)d_out;

  char* ws = (char*)d_ws;
  bf16* q   = (bf16*)(ws);
  bf16* k   = (bf16*)(ws + 67108864ull);
  bf16* v   = (bf16*)(ws + 134217728ull);
  bf16* w1b = (bf16*)(ws + 201326592ull);
  bf16* w2b = (bf16*)(ws + 201326592ull + 1572864ull);

  const int LDS_QKV  = (128 * 512 + 8 * 16 * 72) * 2;             // 149,504 B
  const int LDS_ATTN = (256 * 72 + 64 * 264 + 8 * 16 * 264) * 2;  // 138,240 B
  const int LDS_OUT  = 128 * 512 * 2;                             // 131,072 B
  hipFuncSetAttribute(reinterpret_cast<const void*>(gemm_qkv),
                      hipFuncAttributeMaxDynamicSharedMemorySize, LDS_QKV);
  hipFuncSetAttribute(reinterpret_cast<const void*>(attn_win),
                      hipFuncAttributeMaxDynamicSharedMemorySize, LDS_ATTN);
  hipFuncSetAttribute(reinterpret_cast<const void*>(gemm_out),
                      hipFuncAttributeMaxDynamicSharedMemorySize, LDS_OUT);

  hipLaunchKernelGGL(cvt_fp32_bf16, dim3(768), dim3(256), 0, stream, w1f, w1b);
  hipLaunchKernelGGL(cvt_fp32_bf16, dim3(256), dim3(256), 0, stream, w2f, w2b);
  hipLaunchKernelGGL(gemm_qkv, dim3(512), dim3(512), LDS_QKV, stream, x, w1b, b1, q, k, v);
  hipLaunchKernelGGL(attn_win, dim3(2048), dim3(512), LDS_ATTN, stream, q, k, v);
  hipLaunchKernelGGL(gemm_out, dim3(512), dim3(512), LDS_OUT, stream, q, w2b, b2, out);
}